// Round 6
// baseline (356.213 us; speedup 1.0000x reference)
//
#include <hip/hip_runtime.h>
#include <hip/hip_bf16.h>

#define BB 8
#define CC 512
#define TT 1024
#define HH 8
#define HD 64
#define CLIPW 4
#define NCOUT 512
#define NT 64   // number of 16-wide s-tiles

using bf16 = __hip_bfloat16;
typedef __bf16 bf16x8_t __attribute__((ext_vector_type(8)));
typedef __bf16 bf16x4_t __attribute__((ext_vector_type(4)));
typedef float f32x4_t __attribute__((ext_vector_type(4)));

__device__ __forceinline__ float bf2f(bf16 v) {
  return __uint_as_float(((unsigned int)*(unsigned short*)&v) << 16);
}

// ===========================================================================
// GEMM kernels (unchanged from round 5; ~66 us combined)
// ===========================================================================
__global__ __launch_bounds__(256) void gemm_qkv(
    const float* __restrict__ X,
    const float* __restrict__ Wq, const float* __restrict__ bq,
    const float* __restrict__ Wk, const float* __restrict__ bk,
    const float* __restrict__ Wv, const float* __restrict__ bv,
    bf16* __restrict__ qw, bf16* __restrict__ kw, bf16* __restrict__ vtw) {
  __shared__ __align__(16) char smem[2 * 64 * 72 * 2];
  __bf16* Ws = (__bf16*)smem;
  __bf16* Xs = (__bf16*)(smem + 64 * 72 * 2);

  const int y  = blockIdx.y;
  const int m  = y >> 3;
  const int o0 = (y & 7) * 64;
  const int t0 = blockIdx.x * 64;
  const int b  = blockIdx.z;
  const float* W    = (m == 0) ? Wq : (m == 1) ? Wk : Wv;
  const float* bias = (m == 0) ? bq : (m == 1) ? bk : bv;

  const int tid = threadIdx.x;
  const int w = tid >> 6, l = tid & 63, g = l >> 4, sl = l & 15;
  const int wr = w >> 1, wc = w & 1;

  f32x4_t acc[2][2] = {};
  for (int c0 = 0; c0 < CC; c0 += 64) {
    {
      const int oi = tid >> 4, c4 = (tid & 15) * 4;
#pragma unroll
      for (int op = 0; op < 4; ++op) {
        const int o = op * 16 + oi;
        const float4 w4 = *(const float4*)&W[(size_t)(o0 + o) * CC + c0 + c4];
        bf16x4_t p;
        p[0] = (__bf16)w4.x; p[1] = (__bf16)w4.y;
        p[2] = (__bf16)w4.z; p[3] = (__bf16)w4.w;
        *(bf16x4_t*)&Ws[o * 72 + c4] = p;
      }
    }
    {
      const int t4 = (tid & 15) * 4, ci = tid >> 4;
#pragma unroll
      for (int cp = 0; cp < 4; ++cp) {
        const int c = cp * 16 + ci;
        const float4 x4 = *(const float4*)&X[((size_t)b * CC + c0 + c) * TT + t0 + t4];
        Xs[(t4 + 0) * 72 + c] = (__bf16)x4.x;
        Xs[(t4 + 1) * 72 + c] = (__bf16)x4.y;
        Xs[(t4 + 2) * 72 + c] = (__bf16)x4.z;
        Xs[(t4 + 3) * 72 + c] = (__bf16)x4.w;
      }
    }
    __syncthreads();
#pragma unroll
    for (int kk = 0; kk < 2; ++kk) {
      bf16x8_t a[2], bb[2];
#pragma unroll
      for (int mm = 0; mm < 2; ++mm)
        a[mm] = *(const bf16x8_t*)&Ws[(wr * 32 + mm * 16 + sl) * 72 + kk * 32 + g * 8];
#pragma unroll
      for (int nn = 0; nn < 2; ++nn)
        bb[nn] = *(const bf16x8_t*)&Xs[(wc * 32 + nn * 16 + sl) * 72 + kk * 32 + g * 8];
#pragma unroll
      for (int mm = 0; mm < 2; ++mm)
#pragma unroll
        for (int nn = 0; nn < 2; ++nn)
          acc[mm][nn] = __builtin_amdgcn_mfma_f32_16x16x32_bf16(a[mm], bb[nn], acc[mm][nn], 0, 0, 0);
    }
    __syncthreads();
  }

  float* Cs = (float*)smem;
#pragma unroll
  for (int mm = 0; mm < 2; ++mm)
#pragma unroll
    for (int nn = 0; nn < 2; ++nn)
#pragma unroll
      for (int r = 0; r < 4; ++r)
        Cs[(wr * 32 + mm * 16 + 4 * g + r) * 68 + wc * 32 + nn * 16 + sl] = acc[mm][nn][r];
  __syncthreads();

  if (m < 2) {
    bf16* dst = (m == 0) ? qw : kw;
    const int hh2 = o0 >> 6;
    const int t = tid >> 2, oq = tid & 3;
    bf16x8_t p0, p1;
#pragma unroll
    for (int i = 0; i < 8; ++i) {
      p0[i] = (__bf16)(Cs[(oq * 16 + i) * 68 + t] + bias[o0 + oq * 16 + i]);
      p1[i] = (__bf16)(Cs[(oq * 16 + 8 + i) * 68 + t] + bias[o0 + oq * 16 + 8 + i]);
    }
    bf16* dp = dst + (((size_t)b * HH + hh2) * TT + t0 + t) * HD + oq * 16;
    *(bf16x8_t*)dp = p0;
    *(bf16x8_t*)(dp + 8) = p1;
  } else {
    const int o = tid >> 2, tq = tid & 3;
    const float bv_ = bias[o0 + o];
    bf16x8_t p0, p1;
#pragma unroll
    for (int i = 0; i < 8; ++i) {
      p0[i] = (__bf16)(Cs[o * 68 + tq * 16 + i] + bv_);
      p1[i] = (__bf16)(Cs[o * 68 + tq * 16 + 8 + i] + bv_);
    }
    bf16* dp = vtw + ((size_t)b * CC + o0 + o) * TT + t0 + tq * 16;
    *(bf16x8_t*)dp = p0;
    *(bf16x8_t*)(dp + 8) = p1;
  }
}

__global__ __launch_bounds__(256) void gemm_out(
    const bf16* __restrict__ S, const float* __restrict__ Wp,
    const float* __restrict__ bp, float* __restrict__ out) {
  __shared__ __align__(16) char smem[2 * 64 * 72 * 2];
  __bf16* Ws = (__bf16*)smem;
  __bf16* Xs = (__bf16*)(smem + 64 * 72 * 2);

  const int o0 = blockIdx.y * 64;
  const int t0 = blockIdx.x * 64;
  const int b  = blockIdx.z;
  const int tid = threadIdx.x;
  const int w = tid >> 6, l = tid & 63, g = l >> 4, sl = l & 15;
  const int wr = w >> 1, wc = w & 1;

  f32x4_t acc[2][2] = {};
  for (int c0 = 0; c0 < CC; c0 += 64) {
    {
      const int oi = tid >> 4, c4 = (tid & 15) * 4;
#pragma unroll
      for (int op = 0; op < 4; ++op) {
        const int o = op * 16 + oi;
        const float4 w4 = *(const float4*)&Wp[(size_t)(o0 + o) * CC + c0 + c4];
        bf16x4_t p;
        p[0] = (__bf16)w4.x; p[1] = (__bf16)w4.y;
        p[2] = (__bf16)w4.z; p[3] = (__bf16)w4.w;
        *(bf16x4_t*)&Ws[o * 72 + c4] = p;
      }
    }
    {
      const int t4 = (tid & 15) * 4, ci = tid >> 4;
#pragma unroll
      for (int cp = 0; cp < 4; ++cp) {
        const int c = cp * 16 + ci;
        const bf16x4_t x4 = *(const bf16x4_t*)&S[((size_t)b * CC + c0 + c) * TT + t0 + t4];
        Xs[(t4 + 0) * 72 + c] = x4[0];
        Xs[(t4 + 1) * 72 + c] = x4[1];
        Xs[(t4 + 2) * 72 + c] = x4[2];
        Xs[(t4 + 3) * 72 + c] = x4[3];
      }
    }
    __syncthreads();
#pragma unroll
    for (int kk = 0; kk < 2; ++kk) {
      bf16x8_t a[2], bb[2];
#pragma unroll
      for (int mm = 0; mm < 2; ++mm)
        a[mm] = *(const bf16x8_t*)&Ws[(wr * 32 + mm * 16 + sl) * 72 + kk * 32 + g * 8];
#pragma unroll
      for (int nn = 0; nn < 2; ++nn)
        bb[nn] = *(const bf16x8_t*)&Xs[(wc * 32 + nn * 16 + sl) * 72 + kk * 32 + g * 8];
#pragma unroll
      for (int mm = 0; mm < 2; ++mm)
#pragma unroll
        for (int nn = 0; nn < 2; ++nn)
          acc[mm][nn] = __builtin_amdgcn_mfma_f32_16x16x32_bf16(a[mm], bb[nn], acc[mm][nn], 0, 0, 0);
    }
    __syncthreads();
  }

  float* Cs = (float*)smem;
#pragma unroll
  for (int mm = 0; mm < 2; ++mm)
#pragma unroll
    for (int nn = 0; nn < 2; ++nn)
#pragma unroll
      for (int r = 0; r < 4; ++r)
        Cs[(wr * 32 + mm * 16 + 4 * g + r) * 68 + wc * 32 + nn * 16 + sl] = acc[mm][nn][r];
  __syncthreads();

  const int o = tid >> 2, tq = tid & 3;
  const float bv_ = bp[o0 + o];
  float* dp = out + ((size_t)b * NCOUT + o0 + o) * TT + t0 + tq * 16;
#pragma unroll
  for (int i4 = 0; i4 < 4; ++i4) {
    f32x4_t v = *(const f32x4_t*)&Cs[o * 68 + tq * 16 + i4 * 4];
    v[0] += bv_; v[1] += bv_; v[2] += bv_; v[3] += bv_;
    *(f32x4_t*)(dp + i4 * 4) = v;
  }
}

// ===========================================================================
// attn v3: one wave = 16 q-rows x full s. No __syncthreads anywhere.
//   swapped QK: accT lane(g,ql) reg r -> (q=ql, s=st*16+4g+r)
//   pass1: QK + exp (no max-sub; scores |x|<~8) -> bf16 stash[64] + lsum
//   pass2: per 2 tiles: normalize -> per-wave LDS tile -> coalesced align
//          store + PV B-frag from LDS + 4 PV MFMAs (A = V^T rows).
//   band-K via one MFMA into LDS; band-V via one final MFMA from bandP.
// ===========================================================================
__global__ __launch_bounds__(256, 2) void attn_v3(
    const bf16* __restrict__ qw, const bf16* __restrict__ kw,
    const bf16* __restrict__ vtw,
    const float* __restrict__ wK, const float* __restrict__ wV,
    float* __restrict__ align_out, bf16* __restrict__ attnw) {
  const int h  = blockIdx.y;
  const int b  = blockIdx.z;
  const int bh = b * HH + h;
  const int tid = threadIdx.x;
  const int w = tid >> 6, l = tid & 63, g = l >> 4, ql = l & 15;
  const int q0  = blockIdx.x * 64 + w * 16;
  const int q0s = __builtin_amdgcn_readfirstlane(q0);
  const int qabs = q0 + ql;

  __shared__ float bandv[4][16][12];
  __shared__ float bandP[4][16][36];
  __shared__ __align__(16) float Bt[4][2][16][20];

  // zero this wave's bandP region (576 floats / 64 lanes = 9 each)
#pragma unroll
  for (int i = 0; i < 9; ++i) {
    const int idx = l * 9 + i;
    bandP[w][idx / 36][idx % 36] = 0.f;
  }

  // Q fragments: lane ql -> q-row q0+ql
  const bf16* qb = qw + ((size_t)bh * TT + q0 + ql) * HD + g * 8;
  const bf16x8_t qa0 = *(const bf16x8_t*)qb;
  const bf16x8_t qa1 = *(const bf16x8_t*)(qb + 32);

  // band-K: one MFMA, A = wK rows (j), B = Q cols (q). D[j][q] at lane(g,ql)
  // reg r = band[j=4g+r][q=ql] -> bandv[w][ql][j]
  {
    const int j = (ql < 9) ? ql : 0;
    const float* wkr = wK + j * HD + g * 8;
    const f32x4_t w0 = *(const f32x4_t*)wkr;
    const f32x4_t w1 = *(const f32x4_t*)(wkr + 4);
    const f32x4_t w2 = *(const f32x4_t*)(wkr + 32);
    const f32x4_t w3 = *(const f32x4_t*)(wkr + 36);
    bf16x8_t ka0, ka1;
#pragma unroll
    for (int i = 0; i < 4; ++i) {
      ka0[i] = (__bf16)w0[i]; ka0[4 + i] = (__bf16)w1[i];
      ka1[i] = (__bf16)w2[i]; ka1[4 + i] = (__bf16)w3[i];
    }
    f32x4_t bacc = {0.f, 0.f, 0.f, 0.f};
    bacc = __builtin_amdgcn_mfma_f32_16x16x32_bf16(ka0, qa0, bacc, 0, 0, 0);
    bacc = __builtin_amdgcn_mfma_f32_16x16x32_bf16(ka1, qa1, bacc, 0, 0, 0);
#pragma unroll
    for (int r = 0; r < 4; ++r)
      if (4 * g + r < 9) bandv[w][ql][4 * g + r] = bacc[r];
  }
  __asm__ volatile("s_waitcnt lgkmcnt(0)" ::: "memory");
  __builtin_amdgcn_sched_barrier(0);

  // ---- pass 1: QK + exp + bf16 stash + lsum ----
  float ls0 = 0.f, ls1 = 0.f, ls2 = 0.f, ls3 = 0.f;
  bf16x4_t stash[NT];
#pragma unroll
  for (int st = 0; st < NT; ++st) {
    const bf16* kb = kw + ((size_t)bh * TT + st * 16 + ql) * HD + g * 8;
    const bf16x8_t k0 = *(const bf16x8_t*)kb;
    const bf16x8_t k1 = *(const bf16x8_t*)(kb + 32);
    f32x4_t a = {0.f, 0.f, 0.f, 0.f};
    a = __builtin_amdgcn_mfma_f32_16x16x32_bf16(k0, qa0, a, 0, 0, 0);
    a = __builtin_amdgcn_mfma_f32_16x16x32_bf16(k1, qa1, a, 0, 0, 0);
    const bool near = (st * 16 + 15 >= q0s - CLIPW) && (st * 16 <= q0s + 15 + CLIPW);
    float e[4];
#pragma unroll
    for (int r = 0; r < 4; ++r) {
      float x = a[r];
      if (near) {
        const int delta = st * 16 + 4 * g + r - qabs;
        if ((unsigned)(delta + CLIPW) <= 2 * CLIPW) x += bandv[w][ql][delta + CLIPW];
      }
      e[r] = __expf(x * 0.125f);
      stash[st][r] = (__bf16)e[r];
    }
    ls0 += e[0]; ls1 += e[1]; ls2 += e[2]; ls3 += e[3];
  }
  float lsum = (ls0 + ls1) + (ls2 + ls3);
  lsum += __shfl_xor(lsum, 16);
  lsum += __shfl_xor(lsum, 32);
  const float inv = 1.0f / lsum;

  // ---- pass 2: normalize -> LDS -> align store + PV ----
  f32x4_t oacc[4] = {};
#pragma unroll
  for (int st2 = 0; st2 < NT / 2; ++st2) {
#pragma unroll
    for (int h2 = 0; h2 < 2; ++h2) {
      const int st = st2 * 2 + h2;
      const bool near = (st * 16 + 15 >= q0s - CLIPW) && (st * 16 <= q0s + 15 + CLIPW);
#pragma unroll
      for (int r = 0; r < 4; ++r) {
        const float p = (float)stash[st][r] * inv;
        if (near) {
          const int delta = st * 16 + 4 * g + r - qabs;
          if ((unsigned)(delta + CLIPW) <= 2 * CLIPW) bandP[w][ql][delta + CLIPW] = p;
        }
        Bt[w][h2][ql][4 * g + r] = p;
      }
    }
    __asm__ volatile("s_waitcnt lgkmcnt(0)" ::: "memory");
    __builtin_amdgcn_sched_barrier(0);

    // alignments: lane -> (q=l&15, 4 s at (l>>4)*4); 16 rows x 64B dense
    {
      const int qr = l & 15, sc = l >> 4;
      float* gp0 = align_out + ((size_t)bh * TT + q0 + qr) * TT + st2 * 32 + sc * 4;
      *(f32x4_t*)gp0        = *(const f32x4_t*)&Bt[w][0][qr][sc * 4];
      *(f32x4_t*)(gp0 + 16) = *(const f32x4_t*)&Bt[w][1][qr][sc * 4];
    }

    // PV B-frag: lane (g,ql) needs p(q=ql, s32=g*8+j) -> Bt[w][g>>1][ql][8*(g&1)+j]
    bf16x8_t pb;
    {
      const float* src = &Bt[w][g >> 1][ql][8 * (g & 1)];
      const f32x4_t p0 = *(const f32x4_t*)src;
      const f32x4_t p1 = *(const f32x4_t*)(src + 4);
#pragma unroll
      for (int i = 0; i < 4; ++i) {
        pb[i] = (__bf16)p0[i];
        pb[4 + i] = (__bf16)p1[i];
      }
    }
#pragma unroll
    for (int dt = 0; dt < 4; ++dt) {
      const bf16x8_t va =
          *(const bf16x8_t*)&vtw[((size_t)bh * HD + dt * 16 + ql) * TT + st2 * 32 + g * 8];
      oacc[dt] = __builtin_amdgcn_mfma_f32_16x16x32_bf16(va, pb, oacc[dt], 0, 0, 0);
    }
  }

  // ---- band-V: one MFMA set. A = wV^T rows (d), B = bandP cols (q) ----
  __asm__ volatile("s_waitcnt lgkmcnt(0)" ::: "memory");
  __builtin_amdgcn_sched_barrier(0);
#pragma unroll
  for (int dt = 0; dt < 4; ++dt) {
    bf16x8_t wa;
#pragma unroll
    for (int jj = 0; jj < 8; ++jj) {
      const int j = g * 8 + jj;
      float v = 0.f;
      if (j < 9) v = wV[j * HD + dt * 16 + ql];
      wa[jj] = (__bf16)v;
    }
    const f32x4_t b0 = *(const f32x4_t*)&bandP[w][ql][g * 8];
    const f32x4_t b1 = *(const f32x4_t*)&bandP[w][ql][g * 8 + 4];
    bf16x8_t pbb;
#pragma unroll
    for (int i = 0; i < 4; ++i) {
      pbb[i] = (__bf16)b0[i];
      pbb[4 + i] = (__bf16)b1[i];
    }
    oacc[dt] = __builtin_amdgcn_mfma_f32_16x16x32_bf16(wa, pbb, oacc[dt], 0, 0, 0);
  }

  // ---- store attn [b][c][t] bf16: lane(g,ql) reg r -> d=dt*16+4g+r, t=q0+ql
#pragma unroll
  for (int dt = 0; dt < 4; ++dt)
#pragma unroll
    for (int r = 0; r < 4; ++r)
      attnw[((size_t)b * CC + h * HD + dt * 16 + 4 * g + r) * TT + q0 + ql] =
          __float2bfloat16(oacc[dt][r]);
}

extern "C" void kernel_launch(void* const* d_in, const int* in_sizes, int n_in,
                              void* d_out, int out_size, void* d_ws, size_t ws_size,
                              hipStream_t stream) {
  const float* X  = (const float*)d_in[0];
  const float* Wq = (const float*)d_in[1];
  const float* bq = (const float*)d_in[2];
  const float* Wk = (const float*)d_in[3];
  const float* bk = (const float*)d_in[4];
  const float* Wv = (const float*)d_in[5];
  const float* bv = (const float*)d_in[6];
  const float* Wp = (const float*)d_in[7];
  const float* bp = (const float*)d_in[8];
  const float* wK = (const float*)d_in[9];
  const float* wV = (const float*)d_in[10];

  float* out       = (float*)d_out;
  float* align_out = out + (size_t)BB * NCOUT * TT;

  const size_t SZ = (size_t)BB * HH * TT * HD;
  bf16* qw    = (bf16*)d_ws;
  bf16* kw    = qw + SZ;
  bf16* vtw   = qw + 2 * SZ;
  bf16* attnw = qw + 3 * SZ;

  gemm_qkv<<<dim3(TT / 64, 24, BB), 256, 0, stream>>>(
      X, Wq, bq, Wk, bk, Wv, bv, qw, kw, vtw);
  attn_v3<<<dim3(TT / 64, HH, BB), 256, 0, stream>>>(
      qw, kw, vtw, wK, wV, align_out, attnw);
  gemm_out<<<dim3(TT / 64, NCOUT / 64, BB), 256, 0, stream>>>(
      attnw, Wp, bp, out);
}

// Round 7
// 240.239 us; speedup vs baseline: 1.4827x; 1.4827x over previous
//
#include <hip/hip_runtime.h>
#include <hip/hip_bf16.h>

#define BB 8
#define CC 512
#define TT 1024
#define HH 8
#define HD 64
#define CLIPW 4
#define NCOUT 512

using bf16 = __hip_bfloat16;
typedef __bf16 bf16x8_t __attribute__((ext_vector_type(8)));
typedef __bf16 bf16x4_t __attribute__((ext_vector_type(4)));
typedef float f32x4_t __attribute__((ext_vector_type(4)));

__device__ __forceinline__ float bf2f(bf16 v) {
  return __uint_as_float(((unsigned int)*(unsigned short*)&v) << 16);
}

// ===========================================================================
// GEMM kernels (unchanged; ~66 us combined)
// ===========================================================================
__global__ __launch_bounds__(256) void gemm_qkv(
    const float* __restrict__ X,
    const float* __restrict__ Wq, const float* __restrict__ bq,
    const float* __restrict__ Wk, const float* __restrict__ bk,
    const float* __restrict__ Wv, const float* __restrict__ bv,
    bf16* __restrict__ qw, bf16* __restrict__ kw, bf16* __restrict__ vtw) {
  __shared__ __align__(16) char smem[2 * 64 * 72 * 2];
  __bf16* Ws = (__bf16*)smem;
  __bf16* Xs = (__bf16*)(smem + 64 * 72 * 2);

  const int y  = blockIdx.y;
  const int m  = y >> 3;
  const int o0 = (y & 7) * 64;
  const int t0 = blockIdx.x * 64;
  const int b  = blockIdx.z;
  const float* W    = (m == 0) ? Wq : (m == 1) ? Wk : Wv;
  const float* bias = (m == 0) ? bq : (m == 1) ? bk : bv;

  const int tid = threadIdx.x;
  const int w = tid >> 6, l = tid & 63, g = l >> 4, sl = l & 15;
  const int wr = w >> 1, wc = w & 1;

  f32x4_t acc[2][2] = {};
  for (int c0 = 0; c0 < CC; c0 += 64) {
    {
      const int oi = tid >> 4, c4 = (tid & 15) * 4;
#pragma unroll
      for (int op = 0; op < 4; ++op) {
        const int o = op * 16 + oi;
        const float4 w4 = *(const float4*)&W[(size_t)(o0 + o) * CC + c0 + c4];
        bf16x4_t p;
        p[0] = (__bf16)w4.x; p[1] = (__bf16)w4.y;
        p[2] = (__bf16)w4.z; p[3] = (__bf16)w4.w;
        *(bf16x4_t*)&Ws[o * 72 + c4] = p;
      }
    }
    {
      const int t4 = (tid & 15) * 4, ci = tid >> 4;
#pragma unroll
      for (int cp = 0; cp < 4; ++cp) {
        const int c = cp * 16 + ci;
        const float4 x4 = *(const float4*)&X[((size_t)b * CC + c0 + c) * TT + t0 + t4];
        Xs[(t4 + 0) * 72 + c] = (__bf16)x4.x;
        Xs[(t4 + 1) * 72 + c] = (__bf16)x4.y;
        Xs[(t4 + 2) * 72 + c] = (__bf16)x4.z;
        Xs[(t4 + 3) * 72 + c] = (__bf16)x4.w;
      }
    }
    __syncthreads();
#pragma unroll
    for (int kk = 0; kk < 2; ++kk) {
      bf16x8_t a[2], bb[2];
#pragma unroll
      for (int mm = 0; mm < 2; ++mm)
        a[mm] = *(const bf16x8_t*)&Ws[(wr * 32 + mm * 16 + sl) * 72 + kk * 32 + g * 8];
#pragma unroll
      for (int nn = 0; nn < 2; ++nn)
        bb[nn] = *(const bf16x8_t*)&Xs[(wc * 32 + nn * 16 + sl) * 72 + kk * 32 + g * 8];
#pragma unroll
      for (int mm = 0; mm < 2; ++mm)
#pragma unroll
        for (int nn = 0; nn < 2; ++nn)
          acc[mm][nn] = __builtin_amdgcn_mfma_f32_16x16x32_bf16(a[mm], bb[nn], acc[mm][nn], 0, 0, 0);
    }
    __syncthreads();
  }

  float* Cs = (float*)smem;
#pragma unroll
  for (int mm = 0; mm < 2; ++mm)
#pragma unroll
    for (int nn = 0; nn < 2; ++nn)
#pragma unroll
      for (int r = 0; r < 4; ++r)
        Cs[(wr * 32 + mm * 16 + 4 * g + r) * 68 + wc * 32 + nn * 16 + sl] = acc[mm][nn][r];
  __syncthreads();

  if (m < 2) {
    bf16* dst = (m == 0) ? qw : kw;
    const int hh2 = o0 >> 6;
    const int t = tid >> 2, oq = tid & 3;
    bf16x8_t p0, p1;
#pragma unroll
    for (int i = 0; i < 8; ++i) {
      p0[i] = (__bf16)(Cs[(oq * 16 + i) * 68 + t] + bias[o0 + oq * 16 + i]);
      p1[i] = (__bf16)(Cs[(oq * 16 + 8 + i) * 68 + t] + bias[o0 + oq * 16 + 8 + i]);
    }
    bf16* dp = dst + (((size_t)b * HH + hh2) * TT + t0 + t) * HD + oq * 16;
    *(bf16x8_t*)dp = p0;
    *(bf16x8_t*)(dp + 8) = p1;
  } else {
    const int o = tid >> 2, tq = tid & 3;
    const float bv_ = bias[o0 + o];
    bf16x8_t p0, p1;
#pragma unroll
    for (int i = 0; i < 8; ++i) {
      p0[i] = (__bf16)(Cs[o * 68 + tq * 16 + i] + bv_);
      p1[i] = (__bf16)(Cs[o * 68 + tq * 16 + 8 + i] + bv_);
    }
    bf16* dp = vtw + ((size_t)b * CC + o0 + o) * TT + t0 + tq * 16;
    *(bf16x8_t*)dp = p0;
    *(bf16x8_t*)(dp + 8) = p1;
  }
}

__global__ __launch_bounds__(256) void gemm_out(
    const bf16* __restrict__ S, const float* __restrict__ Wp,
    const float* __restrict__ bp, float* __restrict__ out) {
  __shared__ __align__(16) char smem[2 * 64 * 72 * 2];
  __bf16* Ws = (__bf16*)smem;
  __bf16* Xs = (__bf16*)(smem + 64 * 72 * 2);

  const int o0 = blockIdx.y * 64;
  const int t0 = blockIdx.x * 64;
  const int b  = blockIdx.z;
  const int tid = threadIdx.x;
  const int w = tid >> 6, l = tid & 63, g = l >> 4, sl = l & 15;
  const int wr = w >> 1, wc = w & 1;

  f32x4_t acc[2][2] = {};
  for (int c0 = 0; c0 < CC; c0 += 64) {
    {
      const int oi = tid >> 4, c4 = (tid & 15) * 4;
#pragma unroll
      for (int op = 0; op < 4; ++op) {
        const int o = op * 16 + oi;
        const float4 w4 = *(const float4*)&Wp[(size_t)(o0 + o) * CC + c0 + c4];
        bf16x4_t p;
        p[0] = (__bf16)w4.x; p[1] = (__bf16)w4.y;
        p[2] = (__bf16)w4.z; p[3] = (__bf16)w4.w;
        *(bf16x4_t*)&Ws[o * 72 + c4] = p;
      }
    }
    {
      const int t4 = (tid & 15) * 4, ci = tid >> 4;
#pragma unroll
      for (int cp = 0; cp < 4; ++cp) {
        const int c = cp * 16 + ci;
        const bf16x4_t x4 = *(const bf16x4_t*)&S[((size_t)b * CC + c0 + c) * TT + t0 + t4];
        Xs[(t4 + 0) * 72 + c] = x4[0];
        Xs[(t4 + 1) * 72 + c] = x4[1];
        Xs[(t4 + 2) * 72 + c] = x4[2];
        Xs[(t4 + 3) * 72 + c] = x4[3];
      }
    }
    __syncthreads();
#pragma unroll
    for (int kk = 0; kk < 2; ++kk) {
      bf16x8_t a[2], bb[2];
#pragma unroll
      for (int mm = 0; mm < 2; ++mm)
        a[mm] = *(const bf16x8_t*)&Ws[(wr * 32 + mm * 16 + sl) * 72 + kk * 32 + g * 8];
#pragma unroll
      for (int nn = 0; nn < 2; ++nn)
        bb[nn] = *(const bf16x8_t*)&Xs[(wc * 32 + nn * 16 + sl) * 72 + kk * 32 + g * 8];
#pragma unroll
      for (int mm = 0; mm < 2; ++mm)
#pragma unroll
        for (int nn = 0; nn < 2; ++nn)
          acc[mm][nn] = __builtin_amdgcn_mfma_f32_16x16x32_bf16(a[mm], bb[nn], acc[mm][nn], 0, 0, 0);
    }
    __syncthreads();
  }

  float* Cs = (float*)smem;
#pragma unroll
  for (int mm = 0; mm < 2; ++mm)
#pragma unroll
    for (int nn = 0; nn < 2; ++nn)
#pragma unroll
      for (int r = 0; r < 4; ++r)
        Cs[(wr * 32 + mm * 16 + 4 * g + r) * 68 + wc * 32 + nn * 16 + sl] = acc[mm][nn][r];
  __syncthreads();

  const int o = tid >> 2, tq = tid & 3;
  const float bv_ = bp[o0 + o];
  float* dp = out + ((size_t)b * NCOUT + o0 + o) * TT + t0 + tq * 16;
#pragma unroll
  for (int i4 = 0; i4 < 4; ++i4) {
    f32x4_t v = *(const f32x4_t*)&Cs[o * 68 + tq * 16 + i4 * 4];
    v[0] += bv_; v[1] += bv_; v[2] += bv_; v[3] += bv_;
    *(f32x4_t*)(dp + i4 * 4) = v;
  }
}

// ===========================================================================
// attn v4: block = 16 q-rows; 4 waves partition s (256 each). XCD-swizzled
// grid so all q-tiles of one (b,h) share an XCD (K/V L2-resident).
// No asm fences (same-wave LDS is in-order). 2 __syncthreads total + epilogue.
// ===========================================================================
__global__ __launch_bounds__(256) void attn_v4(
    const bf16* __restrict__ qw, const bf16* __restrict__ kw,
    const bf16* __restrict__ vtw,
    const float* __restrict__ wK, const float* __restrict__ wV,
    float* __restrict__ align_out, bf16* __restrict__ attnw) {
  // XCD swizzle: fi%8 = XCD; bh ≡ xcd (mod 8) so one (b,h) stays on one XCD.
  const int fi   = blockIdx.x;
  const int xcd  = fi & 7;
  const int k2   = fi >> 3;
  const int bh   = ((k2 >> 6) << 3) + xcd;   // 0..63
  const int qblk = k2 & 63;
  const int b = bh >> 3, h = bh & 7;
  const int q0 = qblk * 16;

  const int tid = threadIdx.x;
  const int w = tid >> 6, l = tid & 63, g = l >> 4, ql = l & 15;
  const int qabs  = q0 + ql;
  const int sbase = w * 256;

  __shared__ __align__(16) char smem[23040];
  float* wbuf   = (float*)smem;              // [4][1088]  Bt(640)/obuf(1088)
  float* bandv  = (float*)(smem + 17408);    // [4][16][12]
  float* bandP  = (float*)(smem + 20480);    // [16][36]
  float* redbuf = (float*)(smem + 22784);    // [4][16]
  float* stg    = (float*)(smem + 17408);    // overlay [64][17] (epilogue)

  // zero bandP (576 floats)
  for (int i = tid; i < 576; i += 256) bandP[i] = 0.f;

  // Q fragments (16 rows per block; same for every wave)
  const bf16* qb = qw + ((size_t)bh * TT + qabs) * HD + g * 8;
  const bf16x8_t qa0 = *(const bf16x8_t*)qb;
  const bf16x8_t qa1 = *(const bf16x8_t*)(qb + 32);

  // band-K per wave: D[j][q] via mfma(A=wK rows, B=Q cols)
  {
    const int j = (ql < 9) ? ql : 0;
    const float* wkr = wK + j * HD + g * 8;
    const f32x4_t w0 = *(const f32x4_t*)wkr;
    const f32x4_t w1 = *(const f32x4_t*)(wkr + 4);
    const f32x4_t w2 = *(const f32x4_t*)(wkr + 32);
    const f32x4_t w3 = *(const f32x4_t*)(wkr + 36);
    bf16x8_t ka0, ka1;
#pragma unroll
    for (int i = 0; i < 4; ++i) {
      ka0[i] = (__bf16)w0[i]; ka0[4 + i] = (__bf16)w1[i];
      ka1[i] = (__bf16)w2[i]; ka1[4 + i] = (__bf16)w3[i];
    }
    f32x4_t bacc = {0.f, 0.f, 0.f, 0.f};
    bacc = __builtin_amdgcn_mfma_f32_16x16x32_bf16(ka0, qa0, bacc, 0, 0, 0);
    bacc = __builtin_amdgcn_mfma_f32_16x16x32_bf16(ka1, qa1, bacc, 0, 0, 0);
#pragma unroll
    for (int r = 0; r < 4; ++r)
      if (4 * g + r < 9) bandv[(w * 16 + ql) * 12 + 4 * g + r] = bacc[r];
  }

  // ---- pass 1: QK + exp (no max-sub) + bf16 stash + partial lsum ----
  float ls = 0.f;
  bf16x4_t stash[16];
#pragma unroll
  for (int st = 0; st < 16; ++st) {
    const int s0t = sbase + st * 16;
    const bf16* kb = kw + ((size_t)bh * TT + s0t + ql) * HD + g * 8;
    const bf16x8_t k0 = *(const bf16x8_t*)kb;
    const bf16x8_t k1 = *(const bf16x8_t*)(kb + 32);
    f32x4_t a = {0.f, 0.f, 0.f, 0.f};
    a = __builtin_amdgcn_mfma_f32_16x16x32_bf16(k0, qa0, a, 0, 0, 0);
    a = __builtin_amdgcn_mfma_f32_16x16x32_bf16(k1, qa1, a, 0, 0, 0);
    const bool near = (s0t + 15 >= q0 - CLIPW) && (s0t <= q0 + 15 + CLIPW);
#pragma unroll
    for (int r = 0; r < 4; ++r) {
      float x = a[r];
      if (near) {
        const int delta = s0t + 4 * g + r - qabs;
        if ((unsigned)(delta + CLIPW) <= 2 * CLIPW)
          x += bandv[(w * 16 + ql) * 12 + delta + CLIPW];
      }
      const float e = __expf(x * 0.125f);
      stash[st][r] = (__bf16)e;
      ls += e;
    }
  }
  ls += __shfl_xor(ls, 16);
  ls += __shfl_xor(ls, 32);
  if (l < 16) redbuf[w * 16 + ql] = ls;
  __syncthreads();
  const float inv = 1.0f / (redbuf[ql] + redbuf[16 + ql] + redbuf[32 + ql] + redbuf[48 + ql]);

  // ---- pass 2: normalize -> per-wave LDS tile -> align store + PV ----
  f32x4_t oacc[4] = {};
  float* Bt = wbuf + w * 1088;
#pragma unroll
  for (int i2 = 0; i2 < 8; ++i2) {
#pragma unroll
    for (int h2 = 0; h2 < 2; ++h2) {
      const int st = i2 * 2 + h2;
      const int s0t = sbase + st * 16;
      const bool near = (s0t + 15 >= q0 - CLIPW) && (s0t <= q0 + 15 + CLIPW);
      f32x4_t p4;
#pragma unroll
      for (int r = 0; r < 4; ++r) {
        const float p = (float)stash[st][r] * inv;
        p4[r] = p;
        if (near) {
          const int delta = s0t + 4 * g + r - qabs;
          if ((unsigned)(delta + CLIPW) <= 2 * CLIPW)
            bandP[ql * 36 + delta + CLIPW] = p;
        }
      }
      *(f32x4_t*)&Bt[h2 * 320 + ql * 20 + 4 * g] = p4;
    }
    // alignments: dense 64B/row (nontemporal stream)
    {
      const int qr = l & 15, sc = l >> 4;
      float* gp = align_out + ((size_t)bh * TT + q0 + qr) * TT + sbase + i2 * 32 + sc * 4;
      __builtin_nontemporal_store(*(const f32x4_t*)&Bt[qr * 20 + sc * 4], (f32x4_t*)gp);
      __builtin_nontemporal_store(*(const f32x4_t*)&Bt[320 + qr * 20 + sc * 4],
                                  (f32x4_t*)(gp + 16));
    }
    // PV B-frag from Bt; A = V^T rows
    bf16x8_t pb;
    {
      const float* src = &Bt[(g >> 1) * 320 + ql * 20 + 8 * (g & 1)];
      const f32x4_t p0 = *(const f32x4_t*)src;
      const f32x4_t p1 = *(const f32x4_t*)(src + 4);
#pragma unroll
      for (int i = 0; i < 4; ++i) {
        pb[i] = (__bf16)p0[i];
        pb[4 + i] = (__bf16)p1[i];
      }
    }
#pragma unroll
    for (int dt = 0; dt < 4; ++dt) {
      const bf16x8_t va =
          *(const bf16x8_t*)&vtw[((size_t)bh * HD + dt * 16 + ql) * TT + sbase + i2 * 32 + g * 8];
      oacc[dt] = __builtin_amdgcn_mfma_f32_16x16x32_bf16(va, pb, oacc[dt], 0, 0, 0);
    }
  }

  // ---- PV partials to LDS (obuf overlays Bt; own wave done with Bt) ----
#pragma unroll
  for (int dt = 0; dt < 4; ++dt)
    *(f32x4_t*)&wbuf[w * 1088 + ql * 68 + dt * 16 + 4 * g] = oacc[dt];
  __syncthreads();

  // ---- epilogue (wave 0): reduce + band-V MFMA + store attn ----
  if (w == 0) {
    f32x4_t osum[4];
#pragma unroll
    for (int dt = 0; dt < 4; ++dt) {
      const int off = ql * 68 + dt * 16 + 4 * g;
      osum[dt] = *(const f32x4_t*)&wbuf[off] + *(const f32x4_t*)&wbuf[1088 + off] +
                 *(const f32x4_t*)&wbuf[2176 + off] + *(const f32x4_t*)&wbuf[3264 + off];
    }
    const f32x4_t b0 = *(const f32x4_t*)&bandP[ql * 36 + g * 8];
    const f32x4_t b1 = *(const f32x4_t*)&bandP[ql * 36 + g * 8 + 4];
    bf16x8_t pbb;
#pragma unroll
    for (int i = 0; i < 4; ++i) {
      pbb[i] = (__bf16)b0[i];
      pbb[4 + i] = (__bf16)b1[i];
    }
#pragma unroll
    for (int dt = 0; dt < 4; ++dt) {
      bf16x8_t wa;
#pragma unroll
      for (int jj = 0; jj < 8; ++jj) {
        const int j = g * 8 + jj;
        wa[jj] = (__bf16)((j < 9) ? wV[j * HD + dt * 16 + ql] : 0.f);
      }
      osum[dt] = __builtin_amdgcn_mfma_f32_16x16x32_bf16(wa, pbb, osum[dt], 0, 0, 0);
    }
    // transpose via stg[64][17], then 2x16B rows per lane
#pragma unroll
    for (int dt = 0; dt < 4; ++dt)
#pragma unroll
      for (int r = 0; r < 4; ++r)
        stg[(dt * 16 + 4 * g + r) * 17 + ql] = osum[dt][r];
    bf16x8_t o0, o1;
#pragma unroll
    for (int i = 0; i < 8; ++i) {
      o0[i] = (__bf16)stg[l * 17 + i];
      o1[i] = (__bf16)stg[l * 17 + 8 + i];
    }
    bf16* dp = attnw + ((size_t)b * CC + h * HD + l) * TT + q0;
    *(bf16x8_t*)dp = o0;
    *(bf16x8_t*)(dp + 8) = o1;
  }
}

extern "C" void kernel_launch(void* const* d_in, const int* in_sizes, int n_in,
                              void* d_out, int out_size, void* d_ws, size_t ws_size,
                              hipStream_t stream) {
  const float* X  = (const float*)d_in[0];
  const float* Wq = (const float*)d_in[1];
  const float* bq = (const float*)d_in[2];
  const float* Wk = (const float*)d_in[3];
  const float* bk = (const float*)d_in[4];
  const float* Wv = (const float*)d_in[5];
  const float* bv = (const float*)d_in[6];
  const float* Wp = (const float*)d_in[7];
  const float* bp = (const float*)d_in[8];
  const float* wK = (const float*)d_in[9];
  const float* wV = (const float*)d_in[10];

  float* out       = (float*)d_out;
  float* align_out = out + (size_t)BB * NCOUT * TT;

  const size_t SZ = (size_t)BB * HH * TT * HD;
  bf16* qw    = (bf16*)d_ws;
  bf16* kw    = qw + SZ;
  bf16* vtw   = qw + 2 * SZ;
  bf16* attnw = qw + 3 * SZ;

  gemm_qkv<<<dim3(TT / 64, 24, BB), 256, 0, stream>>>(
      X, Wq, bq, Wk, bk, Wv, bv, qw, kw, vtw);
  attn_v4<<<dim3(4096), 256, 0, stream>>>(
      qw, kw, vtw, wK, wV, align_out, attnw);
  gemm_out<<<dim3(TT / 64, NCOUT / 64, BB), 256, 0, stream>>>(
      attnw, Wp, bp, out);
}